// Round 19
// baseline (80.061 us; speedup 1.0000x reference)
//
#include <hip/hip_runtime.h>
#include <math.h>

// PointConv round 19: BISECT step — r16 verbatim except window enumeration.
//   k_edges: wave g processes windows covering edges start[16g]..start[16g+16)
//     (group-derived bounds) instead of fixed 64-aligned windows. Ballot
//     segmentation, snidw atomic flush, per-window d2acc, ndw>16 fallback,
//     zero pass, (256,6): ALL byte-identical to r16 (66.1us verified).
//   Single-variable experiment: isolates "group-derived loop bounds" as the
//   possible r17/r18 failure cause; standalone value = L2-local atomics.

typedef __attribute__((ext_vector_type(8))) short short8;
typedef __attribute__((ext_vector_type(4))) float f32x4;
typedef __attribute__((ext_vector_type(4))) int   int4v;
typedef __attribute__((ext_vector_type(2))) int   int2v;

union frag_u { int i[4]; short8 v; };

__device__ __forceinline__ float celu1(float x) {
    float m = fminf(x, 0.0f);
    return fmaxf(x, __expf(m) - 1.0f);
}
__device__ __forceinline__ int cvt_pk_bf16(float lo, float hi) {
    int r; asm("v_cvt_pk_bf16_f32 %0, %1, %2" : "=v"(r) : "v"(lo), "v"(hi)); return r;
}

// start[o]=lower_bound(out_index,o); zero agg; pack pos4[i]={pos_in[i],x_in[i]},
// pos_out4[o]={pos_out[o],0}   (r16 verbatim)
__global__ void k_zero_start(const int* __restrict__ oi, int* __restrict__ start,
                             f32x4* __restrict__ agg4, int n_out, int E, int nzero4,
                             const float* __restrict__ pos_in,
                             const float* __restrict__ x_in,
                             f32x4* __restrict__ pos4, int n_in,
                             const float* __restrict__ pos_out,
                             f32x4* __restrict__ pos_out4) {
    const int t = blockIdx.x * blockDim.x + threadIdx.x;
    if (t <= E) {
        const int cur  = (t < E) ? oi[t] : n_out;
        const int prev = (t > 0) ? oi[t - 1] : -1;
        for (int o = prev + 1; o <= cur; ++o) start[o] = t;
    }
    if (pos4 != nullptr && t < n_in) {
        f32x4 v;
        v.x = pos_in[t*3+0]; v.y = pos_in[t*3+1]; v.z = pos_in[t*3+2];
        v.w = x_in[t];
        pos4[t] = v;
    }
    if (pos_out4 != nullptr && t < n_out) {
        f32x4 v;
        v.x = pos_out[t*3+0]; v.y = pos_out[t*3+1]; v.z = pos_out[t*3+2];
        v.w = 0.0f;
        pos_out4[t] = v;
    }
    const f32x4 z = {0.f, 0.f, 0.f, 0.f};
    for (int i = t; i < nzero4; i += gridDim.x * blockDim.x) agg4[i] = z;
}

template<int TIER>
__global__ __launch_bounds__(256, 6) void k_edges(
    const float* __restrict__ x_in, const float* __restrict__ pos_in,
    const f32x4* __restrict__ pos4, const f32x4* __restrict__ pos_out4,
    const float* __restrict__ pos_out, const int* __restrict__ in_index,
    const int* __restrict__ out_index,
    const float* __restrict__ W1, const float* __restrict__ W2,
    const int* __restrict__ start,
    float* __restrict__ agg, int E, int n_out, int ngroups)
{
    __shared__ int   hbuf [4][64][10];   // r16 verbatim
    __shared__ float scoef[4][64];
    __shared__ int   srank[4][64];
    __shared__ int   snid [4][64];
    __shared__ int   snidw[4][16];

    const int wv = threadIdx.x >> 6, lane = threadIdx.x & 63;
    const int kcol = lane & 15, q = lane >> 4;

    // B1 = W2 fragments (r16 verbatim)
    frag_u b1[4];
#pragma unroll
    for (int jt = 0; jt < 4; ++jt) {
        const int j = jt * 16 + kcol;
        b1[jt].i[0] = cvt_pk_bf16(W2[(4*q+0)*64 + j], W2[(4*q+1)*64 + j]);
        b1[jt].i[1] = cvt_pk_bf16(W2[(4*q+2)*64 + j], W2[(4*q+3)*64 + j]);
        b1[jt].i[2] = 0; b1[jt].i[3] = 0;
    }
    const f32x4 zero4 = {0.f, 0.f, 0.f, 0.f};

    // --- ONLY change vs r16: window bounds derived from the wave's group ---
    const int g = blockIdx.x * 4 + wv;
    if (g >= ngroups) return;
    const int base = g * 16;
    const int hi   = (base + 16 <= n_out) ? base + 16 : n_out;
    const int gs = start[base];
    const int ge = start[hi];

    for (int w0 = gs; w0 < ge; w0 += 64) {
        const int e = w0 + lane;
        const bool valid = e < ge;
        const int ec = valid ? e : ge - 1;

        const int node = out_index[ec];
        const int idx  = in_index[ec];

        float xv, pix, piy, piz;
        if (TIER >= 1) {
            const f32x4 pv = pos4[idx];
            pix = pv.x; piy = pv.y; piz = pv.z; xv = pv.w;
        } else {
            xv  = x_in[idx];
            pix = pos_in[idx*3+0]; piy = pos_in[idx*3+1]; piz = pos_in[idx*3+2];
        }
        float pox, poy, poz;
        if (TIER >= 2) {
            const f32x4 po = pos_out4[node];
            pox = po.x; poy = po.y; poz = po.z;
        } else {
            pox = pos_out[node*3+0]; poy = pos_out[node*3+1]; poz = pos_out[node*3+2];
        }
        const float coef = valid ? xv : 0.0f;
        const float px = pix - pox;
        const float py = piy - poy;
        const float pz = piz - poz;

        // h[16] for this lane's edge (r16 verbatim)
        int hp[8];
#pragma unroll
        for (int c = 0; c < 8; ++c) {
            const float h0 = celu1(fmaf(pz, W1[32 + 2*c],     fmaf(py, W1[16 + 2*c],     px * W1[2*c])));
            const float h1 = celu1(fmaf(pz, W1[32 + 2*c + 1], fmaf(py, W1[16 + 2*c + 1], px * W1[2*c + 1])));
            hp[c] = cvt_pk_bf16(h0, h1);
        }
        *(int4v*)&hbuf[wv][lane][0] = *(const int4v*)&hp[0];
        *(int4v*)&hbuf[wv][lane][4] = *(const int4v*)&hp[4];

        // ---- window-level segmentation (r16 verbatim) ----
        const int prevn = __shfl_up(node, 1);
        const bool whead = (lane == 0) || (node != prevn);
        const unsigned long long wbal = __ballot(whead);
        const int ndw = __popcll(wbal);

        scoef[wv][lane] = coef;

        if (ndw <= 16) {
            // fast path: window-rank MFMA2, D2 accumulated in registers (r16 verbatim)
            const int wrank = __popcll(wbal & ((2ULL << lane) - 1)) - 1;
            srank[wv][lane] = wrank;
            if (whead) snidw[wv][wrank] = node;

            f32x4 d2acc[4] = {zero4, zero4, zero4, zero4};

#pragma unroll
            for (int Q = 0; Q < 4; ++Q) {
                const int2v a1lo = *(const int2v*)&hbuf[wv][Q*16 + kcol][2*q];
                frag_u a1; a1.i[0] = a1lo.x; a1.i[1] = a1lo.y; a1.i[2] = 0; a1.i[3] = 0;

                const f32x4 c4 = *(const f32x4*)&scoef[wv][Q*16 + 4*q];
                const int4v r4 = *(const int4v*)&srank[wv][Q*16 + 4*q];

                frag_u a2;
                a2.i[0] = cvt_pk_bf16(r4.x == kcol ? c4.x : 0.0f, r4.y == kcol ? c4.y : 0.0f);
                a2.i[1] = cvt_pk_bf16(r4.z == kcol ? c4.z : 0.0f, r4.w == kcol ? c4.w : 0.0f);
                a2.i[2] = 0; a2.i[3] = 0;

#pragma unroll
                for (int jt = 0; jt < 4; ++jt) {
                    f32x4 d1 = __builtin_amdgcn_mfma_f32_16x16x32_bf16(a1.v, b1[jt].v, zero4, 0, 0, 0);
                    frag_u b2;
                    b2.i[0] = cvt_pk_bf16(celu1(d1[0]), celu1(d1[1]));
                    b2.i[1] = cvt_pk_bf16(celu1(d1[2]), celu1(d1[3]));
                    b2.i[2] = 0; b2.i[3] = 0;
                    d2acc[jt] = __builtin_amdgcn_mfma_f32_16x16x32_bf16(a2.v, b2.v, d2acc[jt], 0, 0, 0);
                }
            }

            // ONE atomic phase per window (r16 verbatim)
            const int4v n4 = *(const int4v*)&snidw[wv][4*q & 15];
            float* p0 = agg + (long)n4.x * 64 + kcol;
            float* p1 = agg + (long)n4.y * 64 + kcol;
            float* p2 = agg + (long)n4.z * 64 + kcol;
            float* p3 = agg + (long)n4.w * 64 + kcol;
#pragma unroll
            for (int jt = 0; jt < 4; ++jt) {
                if (4*q + 0 < ndw) unsafeAtomicAdd(p0 + jt * 16, d2acc[jt][0]);
                if (4*q + 1 < ndw) unsafeAtomicAdd(p1 + jt * 16, d2acc[jt][1]);
                if (4*q + 2 < ndw) unsafeAtomicAdd(p2 + jt * 16, d2acc[jt][2]);
                if (4*q + 3 < ndw) unsafeAtomicAdd(p3 + jt * 16, d2acc[jt][3]);
            }
        } else {
            // fallback: verbatim r9 quarter-atomic path (r16 verbatim)
            const unsigned long long qbal = wbal | 0x0001000100010001ULL;
            const unsigned mym = (unsigned)(qbal >> (q * 16)) & 0xFFFFu;
            const int rank = __popc(mym & ((2u << kcol) - 1)) - 1;
            srank[wv][lane] = rank;
            const bool qhead = (qbal >> lane) & 1ull;
            if (qhead) snid[wv][(lane & 48) + rank] = node;

            int ndq[4];
#pragma unroll
            for (int Q = 0; Q < 4; ++Q) ndq[Q] = __popc((unsigned)(qbal >> (Q * 16)) & 0xFFFFu);

#pragma unroll
            for (int Q = 0; Q < 4; ++Q) {
                const int2v a1lo = *(const int2v*)&hbuf[wv][Q*16 + kcol][2*q];
                frag_u a1; a1.i[0] = a1lo.x; a1.i[1] = a1lo.y; a1.i[2] = 0; a1.i[3] = 0;

                const f32x4 c4 = *(const f32x4*)&scoef[wv][Q*16 + 4*q];
                const int4v r4 = *(const int4v*)&srank[wv][Q*16 + 4*q];
                const int4v n4 = *(const int4v*)&snid [wv][Q*16 + 4*q];

                frag_u a2;
                a2.i[0] = cvt_pk_bf16(r4.x == kcol ? c4.x : 0.0f, r4.y == kcol ? c4.y : 0.0f);
                a2.i[1] = cvt_pk_bf16(r4.z == kcol ? c4.z : 0.0f, r4.w == kcol ? c4.w : 0.0f);
                a2.i[2] = 0; a2.i[3] = 0;

                const int nd = ndq[Q];
                float* p0 = agg + (long)n4.x * 64 + kcol;
                float* p1 = agg + (long)n4.y * 64 + kcol;
                float* p2 = agg + (long)n4.z * 64 + kcol;
                float* p3 = agg + (long)n4.w * 64 + kcol;

#pragma unroll
                for (int jt = 0; jt < 4; ++jt) {
                    f32x4 d1 = __builtin_amdgcn_mfma_f32_16x16x32_bf16(a1.v, b1[jt].v, zero4, 0, 0, 0);
                    frag_u b2;
                    b2.i[0] = cvt_pk_bf16(celu1(d1[0]), celu1(d1[1]));
                    b2.i[1] = cvt_pk_bf16(celu1(d1[2]), celu1(d1[3]));
                    b2.i[2] = 0; b2.i[3] = 0;
                    f32x4 d2 = __builtin_amdgcn_mfma_f32_16x16x32_bf16(a2.v, b2.v, zero4, 0, 0, 0);
                    if (4*q + 0 < nd) unsafeAtomicAdd(p0 + jt * 16, d2[0]);
                    if (4*q + 1 < nd) unsafeAtomicAdd(p1 + jt * 16, d2[1]);
                    if (4*q + 2 < nd) unsafeAtomicAdd(p2 + jt * 16, d2[2]);
                    if (4*q + 3 < nd) unsafeAtomicAdd(p3 + jt * 16, d2[3]);
                }
            }
        }
    }
}

__global__ __launch_bounds__(256) void k_out(
    float* __restrict__ agg, const float* __restrict__ W3,
    const float* __restrict__ b3, const int* __restrict__ start,
    int n_out, int ntiles, int totwaves)
{
    const int wv = threadIdx.x >> 6, lane = threadIdx.x & 63;
    const int s = lane & 15, q = lane >> 4;

    frag_u B0[4], B1[4];
    float bias[4];
#pragma unroll
    for (int jt = 0; jt < 4; ++jt) {
        const int j = jt * 16 + s;
        bias[jt] = b3[j];
        B0[jt].i[0] = cvt_pk_bf16(W3[( 4*q+0)*64+j], W3[( 4*q+1)*64+j]);
        B0[jt].i[1] = cvt_pk_bf16(W3[( 4*q+2)*64+j], W3[( 4*q+3)*64+j]);
        B0[jt].i[2] = cvt_pk_bf16(W3[(16+4*q+0)*64+j], W3[(16+4*q+1)*64+j]);
        B0[jt].i[3] = cvt_pk_bf16(W3[(16+4*q+2)*64+j], W3[(16+4*q+3)*64+j]);
        B1[jt].i[0] = cvt_pk_bf16(W3[(32+4*q+0)*64+j], W3[(32+4*q+1)*64+j]);
        B1[jt].i[1] = cvt_pk_bf16(W3[(32+4*q+2)*64+j], W3[(32+4*q+3)*64+j]);
        B1[jt].i[2] = cvt_pk_bf16(W3[(48+4*q+0)*64+j], W3[(48+4*q+1)*64+j]);
        B1[jt].i[3] = cvt_pk_bf16(W3[(48+4*q+2)*64+j], W3[(48+4*q+3)*64+j]);
    }
    const f32x4 zero4 = {0.f, 0.f, 0.f, 0.f};

    for (int tile = blockIdx.x * 4 + wv; tile < ntiles; tile += totwaves) {
        const long base = (long)tile * 16;

        const long row_i = base + s;
        const long row_c = row_i < n_out ? row_i : n_out - 1;
        const float* row = agg + row_c * 64;
        const int dd = start[row_c + 1] - start[row_c];
        const float invd = 1.0f / (float)(dd > 0 ? dd : 1);

        f32x4 r0 = *(const f32x4*)(row +      4*q);
        f32x4 r1 = *(const f32x4*)(row + 16 + 4*q);
        f32x4 r2 = *(const f32x4*)(row + 32 + 4*q);
        f32x4 r3 = *(const f32x4*)(row + 48 + 4*q);
        r0 *= invd; r1 *= invd; r2 *= invd; r3 *= invd;

        frag_u A0, A1;
        A0.i[0] = cvt_pk_bf16(r0.x, r0.y); A0.i[1] = cvt_pk_bf16(r0.z, r0.w);
        A0.i[2] = cvt_pk_bf16(r1.x, r1.y); A0.i[3] = cvt_pk_bf16(r1.z, r1.w);
        A1.i[0] = cvt_pk_bf16(r2.x, r2.y); A1.i[1] = cvt_pk_bf16(r2.z, r2.w);
        A1.i[2] = cvt_pk_bf16(r3.x, r3.y); A1.i[3] = cvt_pk_bf16(r3.z, r3.w);

#pragma unroll
        for (int jt = 0; jt < 4; ++jt) {
            f32x4 d = __builtin_amdgcn_mfma_f32_16x16x32_bf16(A0.v, B0[jt].v, zero4, 0, 0, 0);
            d = __builtin_amdgcn_mfma_f32_16x16x32_bf16(A1.v, B1[jt].v, d, 0, 0, 0);
            const int j = jt * 16 + s;
#pragma unroll
            for (int r = 0; r < 4; ++r) {
                const long nodei = base + 4*q + r;
                if (nodei < n_out) {
                    float v = d[r] + bias[jt];
                    if (isnan(v)) v = 0.0f;
                    else if (isinf(v)) v = (v > 0.0f) ? 1e6f : -1e6f;
                    agg[nodei * 64 + j] = v;
                }
            }
        }
    }
}

extern "C" void kernel_launch(void* const* d_in, const int* in_sizes, int n_in_args,
                              void* d_out, int out_size, void* d_ws, size_t ws_size,
                              hipStream_t stream) {
    const float* x_in      = (const float*)d_in[0];
    const float* pos_in    = (const float*)d_in[1];
    // d_in[2] = batch_in (unused)
    const float* pos_out   = (const float*)d_in[3];
    const int*   in_index  = (const int*)d_in[4];
    const int*   out_index = (const int*)d_in[5];
    const float* W1        = (const float*)d_in[6];
    const float* W2        = (const float*)d_in[7];
    const float* W3        = (const float*)d_in[8];
    const float* b3        = (const float*)d_in[9];
    float* out = (float*)d_out;

    const int n_out = in_sizes[3] / 3;   // pos_out is [N_OUT, 3]
    const int E     = in_sizes[4];
    const int n_in  = in_sizes[0];       // x_in is [N_IN, 1]

    // ws layout: start[n_out+1] | pos4[n_in] | pos_out4[n_out] (tiered)
    int* start = (int*)d_ws;
    const size_t start_bytes = ((size_t)(n_out + 1) * 4 + 255) & ~(size_t)255;
    const size_t need1 = start_bytes + (size_t)n_in * 16;
    const size_t need2 = need1 + (size_t)n_out * 16;
    const int tier = (ws_size >= need2) ? 2 : (ws_size >= need1 ? 1 : 0);
    f32x4* pos4     = tier >= 1 ? (f32x4*)((char*)d_ws + start_bytes) : nullptr;
    f32x4* pos_out4 = tier >= 2 ? (f32x4*)((char*)d_ws + need1) : nullptr;

    {
        const int nzero4 = n_out * 16;                  // n_out*64 floats / 4
        int span = (E + 1) > nzero4 ? (E + 1) : nzero4;
        if (n_in > span) span = n_in;
        dim3 b(256), g((span + 255) / 256);
        k_zero_start<<<g, b, 0, stream>>>(out_index, start, (f32x4*)out, n_out, E,
                                          nzero4, pos_in, x_in, pos4, n_in,
                                          pos_out, pos_out4);
    }

    {
        const int ngroups = (n_out + 15) / 16;        // 16-node group per wave
        const int nblocks = (ngroups + 3) / 4;
        if (tier == 2)
            k_edges<2><<<dim3(nblocks), dim3(256), 0, stream>>>(
                x_in, pos_in, pos4, pos_out4, pos_out, in_index, out_index,
                W1, W2, start, out, E, n_out, ngroups);
        else if (tier == 1)
            k_edges<1><<<dim3(nblocks), dim3(256), 0, stream>>>(
                x_in, pos_in, pos4, pos_out4, pos_out, in_index, out_index,
                W1, W2, start, out, E, n_out, ngroups);
        else
            k_edges<0><<<dim3(nblocks), dim3(256), 0, stream>>>(
                x_in, pos_in, pos4, pos_out4, pos_out, in_index, out_index,
                W1, W2, start, out, E, n_out, ngroups);
    }
    {
        const int ntiles = (n_out + 15) / 16;        // 16 nodes per tile
        const int nblocks = (ntiles + 7) / 8;        // ~2 tiles per wave
        const int totwaves = nblocks * 4;
        k_out<<<dim3(nblocks), dim3(256), 0, stream>>>(
            out, W3, b3, start, n_out, ntiles, totwaves);
    }
}

// Round 20
// 72.561 us; speedup vs baseline: 1.1034x; 1.1034x over previous
//
#include <hip/hip_runtime.h>
#include <math.h>

// PointConv round 20: r16 verbatim (best verified, 66.1us) with the single
// change __launch_bounds__(256,6) -> (256,8) on k_edges (force total regs
// <=64/wave; probes whether registers still cap occupancy at 48%).
//   k_zero_start: CSR offsets + agg zeroing + pos4/pos_out4 packing (tiered).
//   k_edges<TIER>: fixed 64-edge windows, 1 window/wave; window-rank MFMA2,
//     D2 register accumulation, 16 atomics/window; r9 fallback for ndw>16.
//   k_out: deg-norm + W3 MFMA + bias + nan_to_num, in-place.

typedef __attribute__((ext_vector_type(8))) short short8;
typedef __attribute__((ext_vector_type(4))) float f32x4;
typedef __attribute__((ext_vector_type(4))) int   int4v;
typedef __attribute__((ext_vector_type(2))) int   int2v;

union frag_u { int i[4]; short8 v; };

__device__ __forceinline__ float celu1(float x) {
    float m = fminf(x, 0.0f);
    return fmaxf(x, __expf(m) - 1.0f);
}
__device__ __forceinline__ int cvt_pk_bf16(float lo, float hi) {
    int r; asm("v_cvt_pk_bf16_f32 %0, %1, %2" : "=v"(r) : "v"(lo), "v"(hi)); return r;
}

// start[o]=lower_bound(out_index,o); zero agg; pack pos4[i]={pos_in[i],x_in[i]},
// pos_out4[o]={pos_out[o],0}
__global__ void k_zero_start(const int* __restrict__ oi, int* __restrict__ start,
                             f32x4* __restrict__ agg4, int n_out, int E, int nzero4,
                             const float* __restrict__ pos_in,
                             const float* __restrict__ x_in,
                             f32x4* __restrict__ pos4, int n_in,
                             const float* __restrict__ pos_out,
                             f32x4* __restrict__ pos_out4) {
    const int t = blockIdx.x * blockDim.x + threadIdx.x;
    if (t <= E) {
        const int cur  = (t < E) ? oi[t] : n_out;
        const int prev = (t > 0) ? oi[t - 1] : -1;
        for (int o = prev + 1; o <= cur; ++o) start[o] = t;
    }
    if (pos4 != nullptr && t < n_in) {
        f32x4 v;
        v.x = pos_in[t*3+0]; v.y = pos_in[t*3+1]; v.z = pos_in[t*3+2];
        v.w = x_in[t];
        pos4[t] = v;
    }
    if (pos_out4 != nullptr && t < n_out) {
        f32x4 v;
        v.x = pos_out[t*3+0]; v.y = pos_out[t*3+1]; v.z = pos_out[t*3+2];
        v.w = 0.0f;
        pos_out4[t] = v;
    }
    const f32x4 z = {0.f, 0.f, 0.f, 0.f};
    for (int i = t; i < nzero4; i += gridDim.x * blockDim.x) agg4[i] = z;
}

template<int TIER>
__global__ __launch_bounds__(256, 8) void k_edges(
    const float* __restrict__ x_in, const float* __restrict__ pos_in,
    const f32x4* __restrict__ pos4, const f32x4* __restrict__ pos_out4,
    const float* __restrict__ pos_out, const int* __restrict__ in_index,
    const int* __restrict__ out_index,
    const float* __restrict__ W1, const float* __restrict__ W2,
    float* __restrict__ agg, int E, int nwin, int totwaves)
{
    __shared__ int   hbuf [4][64][10];   // padded rows (40B) -> conflict-light reads
    __shared__ float scoef[4][64];
    __shared__ int   srank[4][64];       // window-rank (fast) or quarter-rank (fallback)
    __shared__ int   snid [4][64];       // quarter-rank node ids (fallback path)
    __shared__ int   snidw[4][16];       // window-rank node ids (fast path)

    const int wv = threadIdx.x >> 6, lane = threadIdx.x & 63;
    const int kcol = lane & 15, q = lane >> 4;

    // B1 = W2 fragments: B[kk=4q+i][n=j=jt*16+kcol], K upper half zero
    frag_u b1[4];
#pragma unroll
    for (int jt = 0; jt < 4; ++jt) {
        const int j = jt * 16 + kcol;
        b1[jt].i[0] = cvt_pk_bf16(W2[(4*q+0)*64 + j], W2[(4*q+1)*64 + j]);
        b1[jt].i[1] = cvt_pk_bf16(W2[(4*q+2)*64 + j], W2[(4*q+3)*64 + j]);
        b1[jt].i[2] = 0; b1[jt].i[3] = 0;
    }
    const f32x4 zero4 = {0.f, 0.f, 0.f, 0.f};

    for (int win = blockIdx.x * 4 + wv; win < nwin; win += totwaves) {
        const int e = win * 64 + lane;
        const bool valid = e < E;
        const int ec = valid ? e : E - 1;

        const int node = out_index[ec];
        const int idx  = in_index[ec];

        float xv, pix, piy, piz;
        if (TIER >= 1) {
            const f32x4 pv = pos4[idx];          // ONE scattered 16B gather
            pix = pv.x; piy = pv.y; piz = pv.z; xv = pv.w;
        } else {
            xv  = x_in[idx];
            pix = pos_in[idx*3+0]; piy = pos_in[idx*3+1]; piz = pos_in[idx*3+2];
        }
        float pox, poy, poz;
        if (TIER >= 2) {
            const f32x4 po = pos_out4[node];     // ONE 16B (mostly-broadcast) load
            pox = po.x; poy = po.y; poz = po.z;
        } else {
            pox = pos_out[node*3+0]; poy = pos_out[node*3+1]; poz = pos_out[node*3+2];
        }
        const float coef = valid ? xv : 0.0f;    // unnormalized; deg in k_out
        const float px = pix - pox;
        const float py = piy - poy;
        const float pz = piz - poz;

        // this lane's edge: all 16 h channels
        int hp[8];
#pragma unroll
        for (int c = 0; c < 8; ++c) {
            const float h0 = celu1(fmaf(pz, W1[32 + 2*c],     fmaf(py, W1[16 + 2*c],     px * W1[2*c])));
            const float h1 = celu1(fmaf(pz, W1[32 + 2*c + 1], fmaf(py, W1[16 + 2*c + 1], px * W1[2*c + 1])));
            hp[c] = cvt_pk_bf16(h0, h1);
        }
        *(int4v*)&hbuf[wv][lane][0] = *(const int4v*)&hp[0];
        *(int4v*)&hbuf[wv][lane][4] = *(const int4v*)&hp[4];

        // ---- window-level segmentation ----
        const int prevn = __shfl_up(node, 1);
        const bool whead = (lane == 0) || (node != prevn);
        const unsigned long long wbal = __ballot(whead);
        const int ndw = __popcll(wbal);

        scoef[wv][lane] = coef;

        if (ndw <= 16) {
            // ======== fast path: window-rank MFMA2, D2 accumulated in registers ========
            const int wrank = __popcll(wbal & ((2ULL << lane) - 1)) - 1;
            srank[wv][lane] = wrank;
            if (whead) snidw[wv][wrank] = node;

            f32x4 d2acc[4] = {zero4, zero4, zero4, zero4};

#pragma unroll
            for (int Q = 0; Q < 4; ++Q) {
                const int2v a1lo = *(const int2v*)&hbuf[wv][Q*16 + kcol][2*q];
                frag_u a1; a1.i[0] = a1lo.x; a1.i[1] = a1lo.y; a1.i[2] = 0; a1.i[3] = 0;

                const f32x4 c4 = *(const f32x4*)&scoef[wv][Q*16 + 4*q];
                const int4v r4 = *(const int4v*)&srank[wv][Q*16 + 4*q];

                frag_u a2;
                a2.i[0] = cvt_pk_bf16(r4.x == kcol ? c4.x : 0.0f, r4.y == kcol ? c4.y : 0.0f);
                a2.i[1] = cvt_pk_bf16(r4.z == kcol ? c4.z : 0.0f, r4.w == kcol ? c4.w : 0.0f);
                a2.i[2] = 0; a2.i[3] = 0;

#pragma unroll
                for (int jt = 0; jt < 4; ++jt) {
                    f32x4 d1 = __builtin_amdgcn_mfma_f32_16x16x32_bf16(a1.v, b1[jt].v, zero4, 0, 0, 0);
                    frag_u b2;
                    b2.i[0] = cvt_pk_bf16(celu1(d1[0]), celu1(d1[1]));
                    b2.i[1] = cvt_pk_bf16(celu1(d1[2]), celu1(d1[3]));
                    b2.i[2] = 0; b2.i[3] = 0;
                    d2acc[jt] = __builtin_amdgcn_mfma_f32_16x16x32_bf16(a2.v, b2.v, d2acc[jt], 0, 0, 0);
                }
            }

            // ONE atomic phase per window
            const int4v n4 = *(const int4v*)&snidw[wv][4*q & 15];
            float* p0 = agg + (long)n4.x * 64 + kcol;
            float* p1 = agg + (long)n4.y * 64 + kcol;
            float* p2 = agg + (long)n4.z * 64 + kcol;
            float* p3 = agg + (long)n4.w * 64 + kcol;
#pragma unroll
            for (int jt = 0; jt < 4; ++jt) {
                if (4*q + 0 < ndw) unsafeAtomicAdd(p0 + jt * 16, d2acc[jt][0]);
                if (4*q + 1 < ndw) unsafeAtomicAdd(p1 + jt * 16, d2acc[jt][1]);
                if (4*q + 2 < ndw) unsafeAtomicAdd(p2 + jt * 16, d2acc[jt][2]);
                if (4*q + 3 < ndw) unsafeAtomicAdd(p3 + jt * 16, d2acc[jt][3]);
            }
        } else {
            // ======== fallback: verbatim r9 quarter-atomic path ========
            const unsigned long long qbal = wbal | 0x0001000100010001ULL;
            const unsigned mym = (unsigned)(qbal >> (q * 16)) & 0xFFFFu;
            const int rank = __popc(mym & ((2u << kcol) - 1)) - 1;
            srank[wv][lane] = rank;
            const bool qhead = (qbal >> lane) & 1ull;
            if (qhead) snid[wv][(lane & 48) + rank] = node;

            int ndq[4];
#pragma unroll
            for (int Q = 0; Q < 4; ++Q) ndq[Q] = __popc((unsigned)(qbal >> (Q * 16)) & 0xFFFFu);

#pragma unroll
            for (int Q = 0; Q < 4; ++Q) {
                const int2v a1lo = *(const int2v*)&hbuf[wv][Q*16 + kcol][2*q];
                frag_u a1; a1.i[0] = a1lo.x; a1.i[1] = a1lo.y; a1.i[2] = 0; a1.i[3] = 0;

                const f32x4 c4 = *(const f32x4*)&scoef[wv][Q*16 + 4*q];
                const int4v r4 = *(const int4v*)&srank[wv][Q*16 + 4*q];
                const int4v n4 = *(const int4v*)&snid [wv][Q*16 + 4*q];

                frag_u a2;
                a2.i[0] = cvt_pk_bf16(r4.x == kcol ? c4.x : 0.0f, r4.y == kcol ? c4.y : 0.0f);
                a2.i[1] = cvt_pk_bf16(r4.z == kcol ? c4.z : 0.0f, r4.w == kcol ? c4.w : 0.0f);
                a2.i[2] = 0; a2.i[3] = 0;

                const int nd = ndq[Q];
                float* p0 = agg + (long)n4.x * 64 + kcol;
                float* p1 = agg + (long)n4.y * 64 + kcol;
                float* p2 = agg + (long)n4.z * 64 + kcol;
                float* p3 = agg + (long)n4.w * 64 + kcol;

#pragma unroll
                for (int jt = 0; jt < 4; ++jt) {
                    f32x4 d1 = __builtin_amdgcn_mfma_f32_16x16x32_bf16(a1.v, b1[jt].v, zero4, 0, 0, 0);
                    frag_u b2;
                    b2.i[0] = cvt_pk_bf16(celu1(d1[0]), celu1(d1[1]));
                    b2.i[1] = cvt_pk_bf16(celu1(d1[2]), celu1(d1[3]));
                    b2.i[2] = 0; b2.i[3] = 0;
                    f32x4 d2 = __builtin_amdgcn_mfma_f32_16x16x32_bf16(a2.v, b2.v, zero4, 0, 0, 0);
                    if (4*q + 0 < nd) unsafeAtomicAdd(p0 + jt * 16, d2[0]);
                    if (4*q + 1 < nd) unsafeAtomicAdd(p1 + jt * 16, d2[1]);
                    if (4*q + 2 < nd) unsafeAtomicAdd(p2 + jt * 16, d2[2]);
                    if (4*q + 3 < nd) unsafeAtomicAdd(p3 + jt * 16, d2[3]);
                }
            }
        }
    }
}

__global__ __launch_bounds__(256) void k_out(
    float* __restrict__ agg, const float* __restrict__ W3,
    const float* __restrict__ b3, const int* __restrict__ start,
    int n_out, int ntiles, int totwaves)
{
    const int wv = threadIdx.x >> 6, lane = threadIdx.x & 63;
    const int s = lane & 15, q = lane >> 4;

    frag_u B0[4], B1[4];
    float bias[4];
#pragma unroll
    for (int jt = 0; jt < 4; ++jt) {
        const int j = jt * 16 + s;
        bias[jt] = b3[j];
        B0[jt].i[0] = cvt_pk_bf16(W3[( 4*q+0)*64+j], W3[( 4*q+1)*64+j]);
        B0[jt].i[1] = cvt_pk_bf16(W3[( 4*q+2)*64+j], W3[( 4*q+3)*64+j]);
        B0[jt].i[2] = cvt_pk_bf16(W3[(16+4*q+0)*64+j], W3[(16+4*q+1)*64+j]);
        B0[jt].i[3] = cvt_pk_bf16(W3[(16+4*q+2)*64+j], W3[(16+4*q+3)*64+j]);
        B1[jt].i[0] = cvt_pk_bf16(W3[(32+4*q+0)*64+j], W3[(32+4*q+1)*64+j]);
        B1[jt].i[1] = cvt_pk_bf16(W3[(32+4*q+2)*64+j], W3[(32+4*q+3)*64+j]);
        B1[jt].i[2] = cvt_pk_bf16(W3[(48+4*q+0)*64+j], W3[(48+4*q+1)*64+j]);
        B1[jt].i[3] = cvt_pk_bf16(W3[(48+4*q+2)*64+j], W3[(48+4*q+3)*64+j]);
    }
    const f32x4 zero4 = {0.f, 0.f, 0.f, 0.f};

    for (int tile = blockIdx.x * 4 + wv; tile < ntiles; tile += totwaves) {
        const long base = (long)tile * 16;

        const long row_i = base + s;
        const long row_c = row_i < n_out ? row_i : n_out - 1;
        const float* row = agg + row_c * 64;
        const int dd = start[row_c + 1] - start[row_c];
        const float invd = 1.0f / (float)(dd > 0 ? dd : 1);

        f32x4 r0 = *(const f32x4*)(row +      4*q);
        f32x4 r1 = *(const f32x4*)(row + 16 + 4*q);
        f32x4 r2 = *(const f32x4*)(row + 32 + 4*q);
        f32x4 r3 = *(const f32x4*)(row + 48 + 4*q);
        r0 *= invd; r1 *= invd; r2 *= invd; r3 *= invd;

        frag_u A0, A1;
        A0.i[0] = cvt_pk_bf16(r0.x, r0.y); A0.i[1] = cvt_pk_bf16(r0.z, r0.w);
        A0.i[2] = cvt_pk_bf16(r1.x, r1.y); A0.i[3] = cvt_pk_bf16(r1.z, r1.w);
        A1.i[0] = cvt_pk_bf16(r2.x, r2.y); A1.i[1] = cvt_pk_bf16(r2.z, r2.w);
        A1.i[2] = cvt_pk_bf16(r3.x, r3.y); A1.i[3] = cvt_pk_bf16(r3.z, r3.w);

#pragma unroll
        for (int jt = 0; jt < 4; ++jt) {
            f32x4 d = __builtin_amdgcn_mfma_f32_16x16x32_bf16(A0.v, B0[jt].v, zero4, 0, 0, 0);
            d = __builtin_amdgcn_mfma_f32_16x16x32_bf16(A1.v, B1[jt].v, d, 0, 0, 0);
            const int j = jt * 16 + s;
#pragma unroll
            for (int r = 0; r < 4; ++r) {
                const long nodei = base + 4*q + r;
                if (nodei < n_out) {
                    float v = d[r] + bias[jt];
                    if (isnan(v)) v = 0.0f;
                    else if (isinf(v)) v = (v > 0.0f) ? 1e6f : -1e6f;
                    agg[nodei * 64 + j] = v;
                }
            }
        }
    }
}

extern "C" void kernel_launch(void* const* d_in, const int* in_sizes, int n_in_args,
                              void* d_out, int out_size, void* d_ws, size_t ws_size,
                              hipStream_t stream) {
    const float* x_in      = (const float*)d_in[0];
    const float* pos_in    = (const float*)d_in[1];
    // d_in[2] = batch_in (unused)
    const float* pos_out   = (const float*)d_in[3];
    const int*   in_index  = (const int*)d_in[4];
    const int*   out_index = (const int*)d_in[5];
    const float* W1        = (const float*)d_in[6];
    const float* W2        = (const float*)d_in[7];
    const float* W3        = (const float*)d_in[8];
    const float* b3        = (const float*)d_in[9];
    float* out = (float*)d_out;

    const int n_out = in_sizes[3] / 3;   // pos_out is [N_OUT, 3]
    const int E     = in_sizes[4];
    const int n_in  = in_sizes[0];       // x_in is [N_IN, 1]

    // ws layout: start[n_out+1] | pos4[n_in] | pos_out4[n_out] (tiered)
    int* start = (int*)d_ws;
    const size_t start_bytes = ((size_t)(n_out + 1) * 4 + 255) & ~(size_t)255;
    const size_t need1 = start_bytes + (size_t)n_in * 16;
    const size_t need2 = need1 + (size_t)n_out * 16;
    const int tier = (ws_size >= need2) ? 2 : (ws_size >= need1 ? 1 : 0);
    f32x4* pos4     = tier >= 1 ? (f32x4*)((char*)d_ws + start_bytes) : nullptr;
    f32x4* pos_out4 = tier >= 2 ? (f32x4*)((char*)d_ws + need1) : nullptr;

    {
        const int nzero4 = n_out * 16;                  // n_out*64 floats / 4
        int span = (E + 1) > nzero4 ? (E + 1) : nzero4;
        if (n_in > span) span = n_in;
        dim3 b(256), g((span + 255) / 256);
        k_zero_start<<<g, b, 0, stream>>>(out_index, start, (f32x4*)out, n_out, E,
                                          nzero4, pos_in, x_in, pos4, n_in,
                                          pos_out, pos_out4);
    }

    {
        const int nwin = (E + 63) / 64;              // 64 edges per window
        const int nblocks = (nwin + 3) / 4;          // ONE window per wave
        const int totwaves = nblocks * 4;
        if (tier == 2)
            k_edges<2><<<dim3(nblocks), dim3(256), 0, stream>>>(
                x_in, pos_in, pos4, pos_out4, pos_out, in_index, out_index, W1, W2, out, E, nwin, totwaves);
        else if (tier == 1)
            k_edges<1><<<dim3(nblocks), dim3(256), 0, stream>>>(
                x_in, pos_in, pos4, pos_out4, pos_out, in_index, out_index, W1, W2, out, E, nwin, totwaves);
        else
            k_edges<0><<<dim3(nblocks), dim3(256), 0, stream>>>(
                x_in, pos_in, pos4, pos_out4, pos_out, in_index, out_index, W1, W2, out, E, nwin, totwaves);
    }
    {
        const int ntiles = (n_out + 15) / 16;        // 16 nodes per tile
        const int nblocks = (ntiles + 7) / 8;        // ~2 tiles per wave
        const int totwaves = nblocks * 4;
        k_out<<<dim3(nblocks), dim3(256), 0, stream>>>(
            out, W3, b3, start, n_out, ntiles, totwaves);
    }
}

// Round 21
// 66.316 us; speedup vs baseline: 1.2073x; 1.0942x over previous
//
#include <hip/hip_runtime.h>
#include <math.h>

// PointConv round 21: r16 verbatim (66.1us best verified) + interior-store flush.
//   Fast-path flush: window segments s in (0, ndw-1) are nodes fully contained
//   in this window (sorted out_index => contiguous edges) -> their agg rows are
//   touched by NO other window -> plain store instead of atomic (zeros from the
//   zero pass are overwritten). Boundary segments s=0 and s=ndw-1 stay atomic.
//   Everything else identical to r16: (256,6), 1 window/wave, ballot
//   segmentation, register d2acc, r9 fallback for ndw>16, k_out verbatim.

typedef __attribute__((ext_vector_type(8))) short short8;
typedef __attribute__((ext_vector_type(4))) float f32x4;
typedef __attribute__((ext_vector_type(4))) int   int4v;
typedef __attribute__((ext_vector_type(2))) int   int2v;

union frag_u { int i[4]; short8 v; };

__device__ __forceinline__ float celu1(float x) {
    float m = fminf(x, 0.0f);
    return fmaxf(x, __expf(m) - 1.0f);
}
__device__ __forceinline__ int cvt_pk_bf16(float lo, float hi) {
    int r; asm("v_cvt_pk_bf16_f32 %0, %1, %2" : "=v"(r) : "v"(lo), "v"(hi)); return r;
}

// start[o]=lower_bound(out_index,o); zero agg; pack pos4[i]={pos_in[i],x_in[i]},
// pos_out4[o]={pos_out[o],0}
__global__ void k_zero_start(const int* __restrict__ oi, int* __restrict__ start,
                             f32x4* __restrict__ agg4, int n_out, int E, int nzero4,
                             const float* __restrict__ pos_in,
                             const float* __restrict__ x_in,
                             f32x4* __restrict__ pos4, int n_in,
                             const float* __restrict__ pos_out,
                             f32x4* __restrict__ pos_out4) {
    const int t = blockIdx.x * blockDim.x + threadIdx.x;
    if (t <= E) {
        const int cur  = (t < E) ? oi[t] : n_out;
        const int prev = (t > 0) ? oi[t - 1] : -1;
        for (int o = prev + 1; o <= cur; ++o) start[o] = t;
    }
    if (pos4 != nullptr && t < n_in) {
        f32x4 v;
        v.x = pos_in[t*3+0]; v.y = pos_in[t*3+1]; v.z = pos_in[t*3+2];
        v.w = x_in[t];
        pos4[t] = v;
    }
    if (pos_out4 != nullptr && t < n_out) {
        f32x4 v;
        v.x = pos_out[t*3+0]; v.y = pos_out[t*3+1]; v.z = pos_out[t*3+2];
        v.w = 0.0f;
        pos_out4[t] = v;
    }
    const f32x4 z = {0.f, 0.f, 0.f, 0.f};
    for (int i = t; i < nzero4; i += gridDim.x * blockDim.x) agg4[i] = z;
}

template<int TIER>
__global__ __launch_bounds__(256, 6) void k_edges(
    const float* __restrict__ x_in, const float* __restrict__ pos_in,
    const f32x4* __restrict__ pos4, const f32x4* __restrict__ pos_out4,
    const float* __restrict__ pos_out, const int* __restrict__ in_index,
    const int* __restrict__ out_index,
    const float* __restrict__ W1, const float* __restrict__ W2,
    float* __restrict__ agg, int E, int nwin, int totwaves)
{
    __shared__ int   hbuf [4][64][10];   // padded rows (40B) -> conflict-light reads
    __shared__ float scoef[4][64];
    __shared__ int   srank[4][64];       // window-rank (fast) or quarter-rank (fallback)
    __shared__ int   snid [4][64];       // quarter-rank node ids (fallback path)
    __shared__ int   snidw[4][16];       // window-rank node ids (fast path)

    const int wv = threadIdx.x >> 6, lane = threadIdx.x & 63;
    const int kcol = lane & 15, q = lane >> 4;

    // B1 = W2 fragments: B[kk=4q+i][n=j=jt*16+kcol], K upper half zero
    frag_u b1[4];
#pragma unroll
    for (int jt = 0; jt < 4; ++jt) {
        const int j = jt * 16 + kcol;
        b1[jt].i[0] = cvt_pk_bf16(W2[(4*q+0)*64 + j], W2[(4*q+1)*64 + j]);
        b1[jt].i[1] = cvt_pk_bf16(W2[(4*q+2)*64 + j], W2[(4*q+3)*64 + j]);
        b1[jt].i[2] = 0; b1[jt].i[3] = 0;
    }
    const f32x4 zero4 = {0.f, 0.f, 0.f, 0.f};

    for (int win = blockIdx.x * 4 + wv; win < nwin; win += totwaves) {
        const int e = win * 64 + lane;
        const bool valid = e < E;
        const int ec = valid ? e : E - 1;

        const int node = out_index[ec];
        const int idx  = in_index[ec];

        float xv, pix, piy, piz;
        if (TIER >= 1) {
            const f32x4 pv = pos4[idx];          // ONE scattered 16B gather
            pix = pv.x; piy = pv.y; piz = pv.z; xv = pv.w;
        } else {
            xv  = x_in[idx];
            pix = pos_in[idx*3+0]; piy = pos_in[idx*3+1]; piz = pos_in[idx*3+2];
        }
        float pox, poy, poz;
        if (TIER >= 2) {
            const f32x4 po = pos_out4[node];     // ONE 16B (mostly-broadcast) load
            pox = po.x; poy = po.y; poz = po.z;
        } else {
            pox = pos_out[node*3+0]; poy = pos_out[node*3+1]; poz = pos_out[node*3+2];
        }
        const float coef = valid ? xv : 0.0f;    // unnormalized; deg in k_out
        const float px = pix - pox;
        const float py = piy - poy;
        const float pz = piz - poz;

        // this lane's edge: all 16 h channels
        int hp[8];
#pragma unroll
        for (int c = 0; c < 8; ++c) {
            const float h0 = celu1(fmaf(pz, W1[32 + 2*c],     fmaf(py, W1[16 + 2*c],     px * W1[2*c])));
            const float h1 = celu1(fmaf(pz, W1[32 + 2*c + 1], fmaf(py, W1[16 + 2*c + 1], px * W1[2*c + 1])));
            hp[c] = cvt_pk_bf16(h0, h1);
        }
        *(int4v*)&hbuf[wv][lane][0] = *(const int4v*)&hp[0];
        *(int4v*)&hbuf[wv][lane][4] = *(const int4v*)&hp[4];

        // ---- window-level segmentation ----
        const int prevn = __shfl_up(node, 1);
        const bool whead = (lane == 0) || (node != prevn);
        const unsigned long long wbal = __ballot(whead);
        const int ndw = __popcll(wbal);

        scoef[wv][lane] = coef;

        if (ndw <= 16) {
            // ======== fast path: window-rank MFMA2, D2 accumulated in registers ========
            const int wrank = __popcll(wbal & ((2ULL << lane) - 1)) - 1;
            srank[wv][lane] = wrank;
            if (whead) snidw[wv][wrank] = node;

            f32x4 d2acc[4] = {zero4, zero4, zero4, zero4};

#pragma unroll
            for (int Q = 0; Q < 4; ++Q) {
                const int2v a1lo = *(const int2v*)&hbuf[wv][Q*16 + kcol][2*q];
                frag_u a1; a1.i[0] = a1lo.x; a1.i[1] = a1lo.y; a1.i[2] = 0; a1.i[3] = 0;

                const f32x4 c4 = *(const f32x4*)&scoef[wv][Q*16 + 4*q];
                const int4v r4 = *(const int4v*)&srank[wv][Q*16 + 4*q];

                frag_u a2;
                a2.i[0] = cvt_pk_bf16(r4.x == kcol ? c4.x : 0.0f, r4.y == kcol ? c4.y : 0.0f);
                a2.i[1] = cvt_pk_bf16(r4.z == kcol ? c4.z : 0.0f, r4.w == kcol ? c4.w : 0.0f);
                a2.i[2] = 0; a2.i[3] = 0;

#pragma unroll
                for (int jt = 0; jt < 4; ++jt) {
                    f32x4 d1 = __builtin_amdgcn_mfma_f32_16x16x32_bf16(a1.v, b1[jt].v, zero4, 0, 0, 0);
                    frag_u b2;
                    b2.i[0] = cvt_pk_bf16(celu1(d1[0]), celu1(d1[1]));
                    b2.i[1] = cvt_pk_bf16(celu1(d1[2]), celu1(d1[3]));
                    b2.i[2] = 0; b2.i[3] = 0;
                    d2acc[jt] = __builtin_amdgcn_mfma_f32_16x16x32_bf16(a2.v, b2.v, d2acc[jt], 0, 0, 0);
                }
            }

            // ONE flush phase per window: interior segments (fully contained in
            // this window) use plain stores; boundary segments stay atomic.
            const int4v n4 = *(const int4v*)&snidw[wv][4*q & 15];
            float* p0 = agg + (long)n4.x * 64 + kcol;
            float* p1 = agg + (long)n4.y * 64 + kcol;
            float* p2 = agg + (long)n4.z * 64 + kcol;
            float* p3 = agg + (long)n4.w * 64 + kcol;
            const int s0 = 4 * q;
            const bool in0 = (s0 + 0 > 0) && (s0 + 0 < ndw - 1);
            const bool in1 = (s0 + 1 > 0) && (s0 + 1 < ndw - 1);
            const bool in2 = (s0 + 2 > 0) && (s0 + 2 < ndw - 1);
            const bool in3 = (s0 + 3 > 0) && (s0 + 3 < ndw - 1);
#pragma unroll
            for (int jt = 0; jt < 4; ++jt) {
                if (s0 + 0 < ndw) { if (in0) p0[jt*16] = d2acc[jt][0]; else unsafeAtomicAdd(p0 + jt*16, d2acc[jt][0]); }
                if (s0 + 1 < ndw) { if (in1) p1[jt*16] = d2acc[jt][1]; else unsafeAtomicAdd(p1 + jt*16, d2acc[jt][1]); }
                if (s0 + 2 < ndw) { if (in2) p2[jt*16] = d2acc[jt][2]; else unsafeAtomicAdd(p2 + jt*16, d2acc[jt][2]); }
                if (s0 + 3 < ndw) { if (in3) p3[jt*16] = d2acc[jt][3]; else unsafeAtomicAdd(p3 + jt*16, d2acc[jt][3]); }
            }
        } else {
            // ======== fallback: verbatim r9 quarter-atomic path ========
            const unsigned long long qbal = wbal | 0x0001000100010001ULL;
            const unsigned mym = (unsigned)(qbal >> (q * 16)) & 0xFFFFu;
            const int rank = __popc(mym & ((2u << kcol) - 1)) - 1;
            srank[wv][lane] = rank;
            const bool qhead = (qbal >> lane) & 1ull;
            if (qhead) snid[wv][(lane & 48) + rank] = node;

            int ndq[4];
#pragma unroll
            for (int Q = 0; Q < 4; ++Q) ndq[Q] = __popc((unsigned)(qbal >> (Q * 16)) & 0xFFFFu);

#pragma unroll
            for (int Q = 0; Q < 4; ++Q) {
                const int2v a1lo = *(const int2v*)&hbuf[wv][Q*16 + kcol][2*q];
                frag_u a1; a1.i[0] = a1lo.x; a1.i[1] = a1lo.y; a1.i[2] = 0; a1.i[3] = 0;

                const f32x4 c4 = *(const f32x4*)&scoef[wv][Q*16 + 4*q];
                const int4v r4 = *(const int4v*)&srank[wv][Q*16 + 4*q];
                const int4v n4 = *(const int4v*)&snid [wv][Q*16 + 4*q];

                frag_u a2;
                a2.i[0] = cvt_pk_bf16(r4.x == kcol ? c4.x : 0.0f, r4.y == kcol ? c4.y : 0.0f);
                a2.i[1] = cvt_pk_bf16(r4.z == kcol ? c4.z : 0.0f, r4.w == kcol ? c4.w : 0.0f);
                a2.i[2] = 0; a2.i[3] = 0;

                const int nd = ndq[Q];
                float* p0 = agg + (long)n4.x * 64 + kcol;
                float* p1 = agg + (long)n4.y * 64 + kcol;
                float* p2 = agg + (long)n4.z * 64 + kcol;
                float* p3 = agg + (long)n4.w * 64 + kcol;

#pragma unroll
                for (int jt = 0; jt < 4; ++jt) {
                    f32x4 d1 = __builtin_amdgcn_mfma_f32_16x16x32_bf16(a1.v, b1[jt].v, zero4, 0, 0, 0);
                    frag_u b2;
                    b2.i[0] = cvt_pk_bf16(celu1(d1[0]), celu1(d1[1]));
                    b2.i[1] = cvt_pk_bf16(celu1(d1[2]), celu1(d1[3]));
                    b2.i[2] = 0; b2.i[3] = 0;
                    f32x4 d2 = __builtin_amdgcn_mfma_f32_16x16x32_bf16(a2.v, b2.v, zero4, 0, 0, 0);
                    if (4*q + 0 < nd) unsafeAtomicAdd(p0 + jt * 16, d2[0]);
                    if (4*q + 1 < nd) unsafeAtomicAdd(p1 + jt * 16, d2[1]);
                    if (4*q + 2 < nd) unsafeAtomicAdd(p2 + jt * 16, d2[2]);
                    if (4*q + 3 < nd) unsafeAtomicAdd(p3 + jt * 16, d2[3]);
                }
            }
        }
    }
}

__global__ __launch_bounds__(256) void k_out(
    float* __restrict__ agg, const float* __restrict__ W3,
    const float* __restrict__ b3, const int* __restrict__ start,
    int n_out, int ntiles, int totwaves)
{
    const int wv = threadIdx.x >> 6, lane = threadIdx.x & 63;
    const int s = lane & 15, q = lane >> 4;

    frag_u B0[4], B1[4];
    float bias[4];
#pragma unroll
    for (int jt = 0; jt < 4; ++jt) {
        const int j = jt * 16 + s;
        bias[jt] = b3[j];
        B0[jt].i[0] = cvt_pk_bf16(W3[( 4*q+0)*64+j], W3[( 4*q+1)*64+j]);
        B0[jt].i[1] = cvt_pk_bf16(W3[( 4*q+2)*64+j], W3[( 4*q+3)*64+j]);
        B0[jt].i[2] = cvt_pk_bf16(W3[(16+4*q+0)*64+j], W3[(16+4*q+1)*64+j]);
        B0[jt].i[3] = cvt_pk_bf16(W3[(16+4*q+2)*64+j], W3[(16+4*q+3)*64+j]);
        B1[jt].i[0] = cvt_pk_bf16(W3[(32+4*q+0)*64+j], W3[(32+4*q+1)*64+j]);
        B1[jt].i[1] = cvt_pk_bf16(W3[(32+4*q+2)*64+j], W3[(32+4*q+3)*64+j]);
        B1[jt].i[2] = cvt_pk_bf16(W3[(48+4*q+0)*64+j], W3[(48+4*q+1)*64+j]);
        B1[jt].i[3] = cvt_pk_bf16(W3[(48+4*q+2)*64+j], W3[(48+4*q+3)*64+j]);
    }
    const f32x4 zero4 = {0.f, 0.f, 0.f, 0.f};

    for (int tile = blockIdx.x * 4 + wv; tile < ntiles; tile += totwaves) {
        const long base = (long)tile * 16;

        const long row_i = base + s;
        const long row_c = row_i < n_out ? row_i : n_out - 1;
        const float* row = agg + row_c * 64;
        const int dd = start[row_c + 1] - start[row_c];
        const float invd = 1.0f / (float)(dd > 0 ? dd : 1);

        f32x4 r0 = *(const f32x4*)(row +      4*q);
        f32x4 r1 = *(const f32x4*)(row + 16 + 4*q);
        f32x4 r2 = *(const f32x4*)(row + 32 + 4*q);
        f32x4 r3 = *(const f32x4*)(row + 48 + 4*q);
        r0 *= invd; r1 *= invd; r2 *= invd; r3 *= invd;

        frag_u A0, A1;
        A0.i[0] = cvt_pk_bf16(r0.x, r0.y); A0.i[1] = cvt_pk_bf16(r0.z, r0.w);
        A0.i[2] = cvt_pk_bf16(r1.x, r1.y); A0.i[3] = cvt_pk_bf16(r1.z, r1.w);
        A1.i[0] = cvt_pk_bf16(r2.x, r2.y); A1.i[1] = cvt_pk_bf16(r2.z, r2.w);
        A1.i[2] = cvt_pk_bf16(r3.x, r3.y); A1.i[3] = cvt_pk_bf16(r3.z, r3.w);

#pragma unroll
        for (int jt = 0; jt < 4; ++jt) {
            f32x4 d = __builtin_amdgcn_mfma_f32_16x16x32_bf16(A0.v, B0[jt].v, zero4, 0, 0, 0);
            d = __builtin_amdgcn_mfma_f32_16x16x32_bf16(A1.v, B1[jt].v, d, 0, 0, 0);
            const int j = jt * 16 + s;
#pragma unroll
            for (int r = 0; r < 4; ++r) {
                const long nodei = base + 4*q + r;
                if (nodei < n_out) {
                    float v = d[r] + bias[jt];
                    if (isnan(v)) v = 0.0f;
                    else if (isinf(v)) v = (v > 0.0f) ? 1e6f : -1e6f;
                    agg[nodei * 64 + j] = v;
                }
            }
        }
    }
}

extern "C" void kernel_launch(void* const* d_in, const int* in_sizes, int n_in_args,
                              void* d_out, int out_size, void* d_ws, size_t ws_size,
                              hipStream_t stream) {
    const float* x_in      = (const float*)d_in[0];
    const float* pos_in    = (const float*)d_in[1];
    // d_in[2] = batch_in (unused)
    const float* pos_out   = (const float*)d_in[3];
    const int*   in_index  = (const int*)d_in[4];
    const int*   out_index = (const int*)d_in[5];
    const float* W1        = (const float*)d_in[6];
    const float* W2        = (const float*)d_in[7];
    const float* W3        = (const float*)d_in[8];
    const float* b3        = (const float*)d_in[9];
    float* out = (float*)d_out;

    const int n_out = in_sizes[3] / 3;   // pos_out is [N_OUT, 3]
    const int E     = in_sizes[4];
    const int n_in  = in_sizes[0];       // x_in is [N_IN, 1]

    // ws layout: start[n_out+1] | pos4[n_in] | pos_out4[n_out] (tiered)
    int* start = (int*)d_ws;
    const size_t start_bytes = ((size_t)(n_out + 1) * 4 + 255) & ~(size_t)255;
    const size_t need1 = start_bytes + (size_t)n_in * 16;
    const size_t need2 = need1 + (size_t)n_out * 16;
    const int tier = (ws_size >= need2) ? 2 : (ws_size >= need1 ? 1 : 0);
    f32x4* pos4     = tier >= 1 ? (f32x4*)((char*)d_ws + start_bytes) : nullptr;
    f32x4* pos_out4 = tier >= 2 ? (f32x4*)((char*)d_ws + need1) : nullptr;

    {
        const int nzero4 = n_out * 16;                  // n_out*64 floats / 4
        int span = (E + 1) > nzero4 ? (E + 1) : nzero4;
        if (n_in > span) span = n_in;
        dim3 b(256), g((span + 255) / 256);
        k_zero_start<<<g, b, 0, stream>>>(out_index, start, (f32x4*)out, n_out, E,
                                          nzero4, pos_in, x_in, pos4, n_in,
                                          pos_out, pos_out4);
    }

    {
        const int nwin = (E + 63) / 64;              // 64 edges per window
        const int nblocks = (nwin + 3) / 4;          // ONE window per wave
        const int totwaves = nblocks * 4;
        if (tier == 2)
            k_edges<2><<<dim3(nblocks), dim3(256), 0, stream>>>(
                x_in, pos_in, pos4, pos_out4, pos_out, in_index, out_index, W1, W2, out, E, nwin, totwaves);
        else if (tier == 1)
            k_edges<1><<<dim3(nblocks), dim3(256), 0, stream>>>(
                x_in, pos_in, pos4, pos_out4, pos_out, in_index, out_index, W1, W2, out, E, nwin, totwaves);
        else
            k_edges<0><<<dim3(nblocks), dim3(256), 0, stream>>>(
                x_in, pos_in, pos4, pos_out4, pos_out, in_index, out_index, W1, W2, out, E, nwin, totwaves);
    }
    {
        const int ntiles = (n_out + 15) / 16;        // 16 nodes per tile
        const int nblocks = (ntiles + 7) / 8;        // ~2 tiles per wave
        const int totwaves = nblocks * 4;
        k_out<<<dim3(nblocks), dim3(256), 0, stream>>>(
            out, W3, b3, start, n_out, ntiles, totwaves);
    }
}

// Round 22
// 65.762 us; speedup vs baseline: 1.2174x; 1.0084x over previous
//
#include <hip/hip_runtime.h>
#include <math.h>

// PointConv round 22: r21 verbatim + 1-wave (64-thread) blocks for k_edges.
//   Theory: 4-wave blocks phase-align their windows' stall patterns; 1-wave
//   blocks give the CU scheduler 4x more independently-phased units (LDS
//   13.8KB -> 3.5KB/block). Numeric path byte-identical to r21 (verified).
//   k_zero_start / k_out: verbatim.

typedef __attribute__((ext_vector_type(8))) short short8;
typedef __attribute__((ext_vector_type(4))) float f32x4;
typedef __attribute__((ext_vector_type(4))) int   int4v;
typedef __attribute__((ext_vector_type(2))) int   int2v;

union frag_u { int i[4]; short8 v; };

__device__ __forceinline__ float celu1(float x) {
    float m = fminf(x, 0.0f);
    return fmaxf(x, __expf(m) - 1.0f);
}
__device__ __forceinline__ int cvt_pk_bf16(float lo, float hi) {
    int r; asm("v_cvt_pk_bf16_f32 %0, %1, %2" : "=v"(r) : "v"(lo), "v"(hi)); return r;
}

// start[o]=lower_bound(out_index,o); zero agg; pack pos4[i]={pos_in[i],x_in[i]},
// pos_out4[o]={pos_out[o],0}
__global__ void k_zero_start(const int* __restrict__ oi, int* __restrict__ start,
                             f32x4* __restrict__ agg4, int n_out, int E, int nzero4,
                             const float* __restrict__ pos_in,
                             const float* __restrict__ x_in,
                             f32x4* __restrict__ pos4, int n_in,
                             const float* __restrict__ pos_out,
                             f32x4* __restrict__ pos_out4) {
    const int t = blockIdx.x * blockDim.x + threadIdx.x;
    if (t <= E) {
        const int cur  = (t < E) ? oi[t] : n_out;
        const int prev = (t > 0) ? oi[t - 1] : -1;
        for (int o = prev + 1; o <= cur; ++o) start[o] = t;
    }
    if (pos4 != nullptr && t < n_in) {
        f32x4 v;
        v.x = pos_in[t*3+0]; v.y = pos_in[t*3+1]; v.z = pos_in[t*3+2];
        v.w = x_in[t];
        pos4[t] = v;
    }
    if (pos_out4 != nullptr && t < n_out) {
        f32x4 v;
        v.x = pos_out[t*3+0]; v.y = pos_out[t*3+1]; v.z = pos_out[t*3+2];
        v.w = 0.0f;
        pos_out4[t] = v;
    }
    const f32x4 z = {0.f, 0.f, 0.f, 0.f};
    for (int i = t; i < nzero4; i += gridDim.x * blockDim.x) agg4[i] = z;
}

template<int TIER>
__global__ __launch_bounds__(64, 6) void k_edges(
    const float* __restrict__ x_in, const float* __restrict__ pos_in,
    const f32x4* __restrict__ pos4, const f32x4* __restrict__ pos_out4,
    const float* __restrict__ pos_out, const int* __restrict__ in_index,
    const int* __restrict__ out_index,
    const float* __restrict__ W1, const float* __restrict__ W2,
    float* __restrict__ agg, int E, int nwin)
{
    __shared__ int   hbuf [64][10];   // padded rows (40B) -> conflict-light reads
    __shared__ float scoef[64];
    __shared__ int   srank[64];       // window-rank (fast) or quarter-rank (fallback)
    __shared__ int   snid [64];       // quarter-rank node ids (fallback path)
    __shared__ int   snidw[16];       // window-rank node ids (fast path)

    const int lane = threadIdx.x & 63;
    const int kcol = lane & 15, q = lane >> 4;

    // B1 = W2 fragments: B[kk=4q+i][n=j=jt*16+kcol], K upper half zero
    frag_u b1[4];
#pragma unroll
    for (int jt = 0; jt < 4; ++jt) {
        const int j = jt * 16 + kcol;
        b1[jt].i[0] = cvt_pk_bf16(W2[(4*q+0)*64 + j], W2[(4*q+1)*64 + j]);
        b1[jt].i[1] = cvt_pk_bf16(W2[(4*q+2)*64 + j], W2[(4*q+3)*64 + j]);
        b1[jt].i[2] = 0; b1[jt].i[3] = 0;
    }
    const f32x4 zero4 = {0.f, 0.f, 0.f, 0.f};

    const int win = blockIdx.x;
    if (win >= nwin) return;
    {
        const int e = win * 64 + lane;
        const bool valid = e < E;
        const int ec = valid ? e : E - 1;

        const int node = out_index[ec];
        const int idx  = in_index[ec];

        float xv, pix, piy, piz;
        if (TIER >= 1) {
            const f32x4 pv = pos4[idx];          // ONE scattered 16B gather
            pix = pv.x; piy = pv.y; piz = pv.z; xv = pv.w;
        } else {
            xv  = x_in[idx];
            pix = pos_in[idx*3+0]; piy = pos_in[idx*3+1]; piz = pos_in[idx*3+2];
        }
        float pox, poy, poz;
        if (TIER >= 2) {
            const f32x4 po = pos_out4[node];     // ONE 16B (mostly-broadcast) load
            pox = po.x; poy = po.y; poz = po.z;
        } else {
            pox = pos_out[node*3+0]; poy = pos_out[node*3+1]; poz = pos_out[node*3+2];
        }
        const float coef = valid ? xv : 0.0f;    // unnormalized; deg in k_out
        const float px = pix - pox;
        const float py = piy - poy;
        const float pz = piz - poz;

        // this lane's edge: all 16 h channels
        int hp[8];
#pragma unroll
        for (int c = 0; c < 8; ++c) {
            const float h0 = celu1(fmaf(pz, W1[32 + 2*c],     fmaf(py, W1[16 + 2*c],     px * W1[2*c])));
            const float h1 = celu1(fmaf(pz, W1[32 + 2*c + 1], fmaf(py, W1[16 + 2*c + 1], px * W1[2*c + 1])));
            hp[c] = cvt_pk_bf16(h0, h1);
        }
        *(int4v*)&hbuf[lane][0] = *(const int4v*)&hp[0];
        *(int4v*)&hbuf[lane][4] = *(const int4v*)&hp[4];

        // ---- window-level segmentation ----
        const int prevn = __shfl_up(node, 1);
        const bool whead = (lane == 0) || (node != prevn);
        const unsigned long long wbal = __ballot(whead);
        const int ndw = __popcll(wbal);

        scoef[lane] = coef;

        if (ndw <= 16) {
            // ======== fast path: window-rank MFMA2, D2 accumulated in registers ========
            const int wrank = __popcll(wbal & ((2ULL << lane) - 1)) - 1;
            srank[lane] = wrank;
            if (whead) snidw[wrank] = node;

            f32x4 d2acc[4] = {zero4, zero4, zero4, zero4};

#pragma unroll
            for (int Q = 0; Q < 4; ++Q) {
                const int2v a1lo = *(const int2v*)&hbuf[Q*16 + kcol][2*q];
                frag_u a1; a1.i[0] = a1lo.x; a1.i[1] = a1lo.y; a1.i[2] = 0; a1.i[3] = 0;

                const f32x4 c4 = *(const f32x4*)&scoef[Q*16 + 4*q];
                const int4v r4 = *(const int4v*)&srank[Q*16 + 4*q];

                frag_u a2;
                a2.i[0] = cvt_pk_bf16(r4.x == kcol ? c4.x : 0.0f, r4.y == kcol ? c4.y : 0.0f);
                a2.i[1] = cvt_pk_bf16(r4.z == kcol ? c4.z : 0.0f, r4.w == kcol ? c4.w : 0.0f);
                a2.i[2] = 0; a2.i[3] = 0;

#pragma unroll
                for (int jt = 0; jt < 4; ++jt) {
                    f32x4 d1 = __builtin_amdgcn_mfma_f32_16x16x32_bf16(a1.v, b1[jt].v, zero4, 0, 0, 0);
                    frag_u b2;
                    b2.i[0] = cvt_pk_bf16(celu1(d1[0]), celu1(d1[1]));
                    b2.i[1] = cvt_pk_bf16(celu1(d1[2]), celu1(d1[3]));
                    b2.i[2] = 0; b2.i[3] = 0;
                    d2acc[jt] = __builtin_amdgcn_mfma_f32_16x16x32_bf16(a2.v, b2.v, d2acc[jt], 0, 0, 0);
                }
            }

            // ONE flush phase per window: interior segments plain stores,
            // boundary segments atomic (r21-verified).
            const int4v n4 = *(const int4v*)&snidw[4*q & 15];
            float* p0 = agg + (long)n4.x * 64 + kcol;
            float* p1 = agg + (long)n4.y * 64 + kcol;
            float* p2 = agg + (long)n4.z * 64 + kcol;
            float* p3 = agg + (long)n4.w * 64 + kcol;
            const int s0 = 4 * q;
            const bool in0 = (s0 + 0 > 0) && (s0 + 0 < ndw - 1);
            const bool in1 = (s0 + 1 > 0) && (s0 + 1 < ndw - 1);
            const bool in2 = (s0 + 2 > 0) && (s0 + 2 < ndw - 1);
            const bool in3 = (s0 + 3 > 0) && (s0 + 3 < ndw - 1);
#pragma unroll
            for (int jt = 0; jt < 4; ++jt) {
                if (s0 + 0 < ndw) { if (in0) p0[jt*16] = d2acc[jt][0]; else unsafeAtomicAdd(p0 + jt*16, d2acc[jt][0]); }
                if (s0 + 1 < ndw) { if (in1) p1[jt*16] = d2acc[jt][1]; else unsafeAtomicAdd(p1 + jt*16, d2acc[jt][1]); }
                if (s0 + 2 < ndw) { if (in2) p2[jt*16] = d2acc[jt][2]; else unsafeAtomicAdd(p2 + jt*16, d2acc[jt][2]); }
                if (s0 + 3 < ndw) { if (in3) p3[jt*16] = d2acc[jt][3]; else unsafeAtomicAdd(p3 + jt*16, d2acc[jt][3]); }
            }
        } else {
            // ======== fallback: verbatim r9 quarter-atomic path ========
            const unsigned long long qbal = wbal | 0x0001000100010001ULL;
            const unsigned mym = (unsigned)(qbal >> (q * 16)) & 0xFFFFu;
            const int rank = __popc(mym & ((2u << kcol) - 1)) - 1;
            srank[lane] = rank;
            const bool qhead = (qbal >> lane) & 1ull;
            if (qhead) snid[(lane & 48) + rank] = node;

            int ndq[4];
#pragma unroll
            for (int Q = 0; Q < 4; ++Q) ndq[Q] = __popc((unsigned)(qbal >> (Q * 16)) & 0xFFFFu);

#pragma unroll
            for (int Q = 0; Q < 4; ++Q) {
                const int2v a1lo = *(const int2v*)&hbuf[Q*16 + kcol][2*q];
                frag_u a1; a1.i[0] = a1lo.x; a1.i[1] = a1lo.y; a1.i[2] = 0; a1.i[3] = 0;

                const f32x4 c4 = *(const f32x4*)&scoef[Q*16 + 4*q];
                const int4v r4 = *(const int4v*)&srank[Q*16 + 4*q];
                const int4v n4 = *(const int4v*)&snid [Q*16 + 4*q];

                frag_u a2;
                a2.i[0] = cvt_pk_bf16(r4.x == kcol ? c4.x : 0.0f, r4.y == kcol ? c4.y : 0.0f);
                a2.i[1] = cvt_pk_bf16(r4.z == kcol ? c4.z : 0.0f, r4.w == kcol ? c4.w : 0.0f);
                a2.i[2] = 0; a2.i[3] = 0;

                const int nd = ndq[Q];
                float* p0 = agg + (long)n4.x * 64 + kcol;
                float* p1 = agg + (long)n4.y * 64 + kcol;
                float* p2 = agg + (long)n4.z * 64 + kcol;
                float* p3 = agg + (long)n4.w * 64 + kcol;

#pragma unroll
                for (int jt = 0; jt < 4; ++jt) {
                    f32x4 d1 = __builtin_amdgcn_mfma_f32_16x16x32_bf16(a1.v, b1[jt].v, zero4, 0, 0, 0);
                    frag_u b2;
                    b2.i[0] = cvt_pk_bf16(celu1(d1[0]), celu1(d1[1]));
                    b2.i[1] = cvt_pk_bf16(celu1(d1[2]), celu1(d1[3]));
                    b2.i[2] = 0; b2.i[3] = 0;
                    f32x4 d2 = __builtin_amdgcn_mfma_f32_16x16x32_bf16(a2.v, b2.v, zero4, 0, 0, 0);
                    if (4*q + 0 < nd) unsafeAtomicAdd(p0 + jt * 16, d2[0]);
                    if (4*q + 1 < nd) unsafeAtomicAdd(p1 + jt * 16, d2[1]);
                    if (4*q + 2 < nd) unsafeAtomicAdd(p2 + jt * 16, d2[2]);
                    if (4*q + 3 < nd) unsafeAtomicAdd(p3 + jt * 16, d2[3]);
                }
            }
        }
    }
}

__global__ __launch_bounds__(256) void k_out(
    float* __restrict__ agg, const float* __restrict__ W3,
    const float* __restrict__ b3, const int* __restrict__ start,
    int n_out, int ntiles, int totwaves)
{
    const int wv = threadIdx.x >> 6, lane = threadIdx.x & 63;
    const int s = lane & 15, q = lane >> 4;

    frag_u B0[4], B1[4];
    float bias[4];
#pragma unroll
    for (int jt = 0; jt < 4; ++jt) {
        const int j = jt * 16 + s;
        bias[jt] = b3[j];
        B0[jt].i[0] = cvt_pk_bf16(W3[( 4*q+0)*64+j], W3[( 4*q+1)*64+j]);
        B0[jt].i[1] = cvt_pk_bf16(W3[( 4*q+2)*64+j], W3[( 4*q+3)*64+j]);
        B0[jt].i[2] = cvt_pk_bf16(W3[(16+4*q+0)*64+j], W3[(16+4*q+1)*64+j]);
        B0[jt].i[3] = cvt_pk_bf16(W3[(16+4*q+2)*64+j], W3[(16+4*q+3)*64+j]);
        B1[jt].i[0] = cvt_pk_bf16(W3[(32+4*q+0)*64+j], W3[(32+4*q+1)*64+j]);
        B1[jt].i[1] = cvt_pk_bf16(W3[(32+4*q+2)*64+j], W3[(32+4*q+3)*64+j]);
        B1[jt].i[2] = cvt_pk_bf16(W3[(48+4*q+0)*64+j], W3[(48+4*q+1)*64+j]);
        B1[jt].i[3] = cvt_pk_bf16(W3[(48+4*q+2)*64+j], W3[(48+4*q+3)*64+j]);
    }
    const f32x4 zero4 = {0.f, 0.f, 0.f, 0.f};

    for (int tile = blockIdx.x * 4 + wv; tile < ntiles; tile += totwaves) {
        const long base = (long)tile * 16;

        const long row_i = base + s;
        const long row_c = row_i < n_out ? row_i : n_out - 1;
        const float* row = agg + row_c * 64;
        const int dd = start[row_c + 1] - start[row_c];
        const float invd = 1.0f / (float)(dd > 0 ? dd : 1);

        f32x4 r0 = *(const f32x4*)(row +      4*q);
        f32x4 r1 = *(const f32x4*)(row + 16 + 4*q);
        f32x4 r2 = *(const f32x4*)(row + 32 + 4*q);
        f32x4 r3 = *(const f32x4*)(row + 48 + 4*q);
        r0 *= invd; r1 *= invd; r2 *= invd; r3 *= invd;

        frag_u A0, A1;
        A0.i[0] = cvt_pk_bf16(r0.x, r0.y); A0.i[1] = cvt_pk_bf16(r0.z, r0.w);
        A0.i[2] = cvt_pk_bf16(r1.x, r1.y); A0.i[3] = cvt_pk_bf16(r1.z, r1.w);
        A1.i[0] = cvt_pk_bf16(r2.x, r2.y); A1.i[1] = cvt_pk_bf16(r2.z, r2.w);
        A1.i[2] = cvt_pk_bf16(r3.x, r3.y); A1.i[3] = cvt_pk_bf16(r3.z, r3.w);

#pragma unroll
        for (int jt = 0; jt < 4; ++jt) {
            f32x4 d = __builtin_amdgcn_mfma_f32_16x16x32_bf16(A0.v, B0[jt].v, zero4, 0, 0, 0);
            d = __builtin_amdgcn_mfma_f32_16x16x32_bf16(A1.v, B1[jt].v, d, 0, 0, 0);
            const int j = jt * 16 + s;
#pragma unroll
            for (int r = 0; r < 4; ++r) {
                const long nodei = base + 4*q + r;
                if (nodei < n_out) {
                    float v = d[r] + bias[jt];
                    if (isnan(v)) v = 0.0f;
                    else if (isinf(v)) v = (v > 0.0f) ? 1e6f : -1e6f;
                    agg[nodei * 64 + j] = v;
                }
            }
        }
    }
}

extern "C" void kernel_launch(void* const* d_in, const int* in_sizes, int n_in_args,
                              void* d_out, int out_size, void* d_ws, size_t ws_size,
                              hipStream_t stream) {
    const float* x_in      = (const float*)d_in[0];
    const float* pos_in    = (const float*)d_in[1];
    // d_in[2] = batch_in (unused)
    const float* pos_out   = (const float*)d_in[3];
    const int*   in_index  = (const int*)d_in[4];
    const int*   out_index = (const int*)d_in[5];
    const float* W1        = (const float*)d_in[6];
    const float* W2        = (const float*)d_in[7];
    const float* W3        = (const float*)d_in[8];
    const float* b3        = (const float*)d_in[9];
    float* out = (float*)d_out;

    const int n_out = in_sizes[3] / 3;   // pos_out is [N_OUT, 3]
    const int E     = in_sizes[4];
    const int n_in  = in_sizes[0];       // x_in is [N_IN, 1]

    // ws layout: start[n_out+1] | pos4[n_in] | pos_out4[n_out] (tiered)
    int* start = (int*)d_ws;
    const size_t start_bytes = ((size_t)(n_out + 1) * 4 + 255) & ~(size_t)255;
    const size_t need1 = start_bytes + (size_t)n_in * 16;
    const size_t need2 = need1 + (size_t)n_out * 16;
    const int tier = (ws_size >= need2) ? 2 : (ws_size >= need1 ? 1 : 0);
    f32x4* pos4     = tier >= 1 ? (f32x4*)((char*)d_ws + start_bytes) : nullptr;
    f32x4* pos_out4 = tier >= 2 ? (f32x4*)((char*)d_ws + need1) : nullptr;

    {
        const int nzero4 = n_out * 16;                  // n_out*64 floats / 4
        int span = (E + 1) > nzero4 ? (E + 1) : nzero4;
        if (n_in > span) span = n_in;
        dim3 b(256), g((span + 255) / 256);
        k_zero_start<<<g, b, 0, stream>>>(out_index, start, (f32x4*)out, n_out, E,
                                          nzero4, pos_in, x_in, pos4, n_in,
                                          pos_out, pos_out4);
    }

    {
        const int nwin = (E + 63) / 64;              // 64 edges per window
        if (tier == 2)
            k_edges<2><<<dim3(nwin), dim3(64), 0, stream>>>(
                x_in, pos_in, pos4, pos_out4, pos_out, in_index, out_index, W1, W2, out, E, nwin);
        else if (tier == 1)
            k_edges<1><<<dim3(nwin), dim3(64), 0, stream>>>(
                x_in, pos_in, pos4, pos_out4, pos_out, in_index, out_index, W1, W2, out, E, nwin);
        else
            k_edges<0><<<dim3(nwin), dim3(64), 0, stream>>>(
                x_in, pos_in, pos4, pos_out4, pos_out, in_index, out_index, W1, W2, out, E, nwin);
    }
    {
        const int ntiles = (n_out + 15) / 16;        // 16 nodes per tile
        const int nblocks = (ntiles + 7) / 8;        // ~2 tiles per wave
        const int totwaves = nblocks * 4;
        k_out<<<dim3(nblocks), dim3(256), 0, stream>>>(
            out, W3, b3, start, n_out, ntiles, totwaves);
    }
}